// Round 8
// baseline (100.147 us; speedup 1.0000x reference)
//
#include <hip/hip_runtime.h>
#include <hip/hip_bf16.h>

#define BATCH 8
#define SEQ   2048
#define DMS   1024
#define KSZ   128
#define OD    1152   // 1024 + 128

typedef unsigned short u16;
typedef unsigned int   u32;
typedef __attribute__((ext_vector_type(4)))  float  f32x4;
typedef __attribute__((ext_vector_type(16))) float  f32x16;
typedef __attribute__((ext_vector_type(8)))  __bf16 bf16x8;

union U128 { uint4 u4; bf16x8 b8; u16 us[8]; u32 u[4]; };

__device__ inline u16 f2bf(float f) {
  union { __bf16 h; u16 u; } c;
  c.h = (__bf16)f;
  return c.u;
}

__device__ inline float fexp2(float x) {
  float r;
  asm("v_exp_f32 %0, %1" : "=v"(r) : "v"(x));
  return r;
}

__device__ inline f32x4 mfma16(bf16x8 a, bf16x8 b, f32x4 c) {
  return __builtin_amdgcn_mfma_f32_16x16x32_bf16(a, b, c, 0, 0, 0);
}
__device__ inline f32x16 mfma32(bf16x8 a, bf16x8 b, f32x16 c) {
  return __builtin_amdgcn_mfma_f32_32x32x16_bf16(a, b, c, 0, 0, 0);
}

__device__ inline uint4 pack8bf(float4 a, float4 b) {
  U128 w;
  w.us[0] = f2bf(a.x); w.us[1] = f2bf(a.y);
  w.us[2] = f2bf(a.z); w.us[3] = f2bf(a.w);
  w.us[4] = f2bf(b.x); w.us[5] = f2bf(b.y);
  w.us[6] = f2bf(b.z); w.us[7] = f2bf(b.w);
  return w.u4;
}

__device__ inline void glds16(const u16* src, u16* ldsDst) {
  __builtin_amdgcn_global_load_lds(
      (const __attribute__((address_space(1))) u32*)src,
      (__attribute__((address_space(3))) u32*)ldsDst, 16, 0, 0);
}

// Fragment-major layouts (per batch, stride 262144 u16 = 512 KB):
//   Kfrag[(t2*8+ks)*512 + hi*256 + l31*8 + j]          = K[t2*32+l31][ks*16+hi*8+j]
//   Vfrag[((t2*4+vb2)*2+th)*512 + hi*256 + l31*8 + j]  = V[t2*32+th*16+hi*8+j][vb2*32+l31]
#define BSTRIDE 262144

// ---------------------------------------------------------------------------
// Kernel 0: prep — [Wk|Wv] f32 -> bf16 tiles in proj's exact LDS byte order.
// Tile ks (32KB): u16 index = n*64 + (kk ^ ((n&7)<<3)), value W[ks*64+kk][n].
// ---------------------------------------------------------------------------
__global__ void __launch_bounds__(256) prep_kernel(
    const float* __restrict__ Wk, const float* __restrict__ Wv,
    u16* __restrict__ Wtiles)
{
  int T = blockIdx.x * 256 + threadIdx.x;   // 0..32767
  int n  = T & 255;
  int kc = (T >> 8) * 8;                    // 0..1016 step 8
  int ks = kc >> 6;
  int kk = kc & 63;
  const float* src = (n < 128) ? (Wk + n) : (Wv + (n - 128));
  U128 w;
#pragma unroll
  for (int j = 0; j < 8; ++j) w.us[j] = f2bf(src[(size_t)(kc + j) * KSZ]);
  u16* dst = Wtiles + ks * 16384 + n * 64 + (kk ^ ((n & 7) << 3));
  *(uint4*)dst = w.u4;
}

// ---------------------------------------------------------------------------
// Kernel 1: fused K/V projection — NO STORES IN THE BARRIERED LOOP.
// (Store-drain hypothesis: __syncthreads drains vmcnt(0) incl. HBM store
//  retirement; 16x/block was the ~52us plateau. Passthrough moved to attn.)
// BM=32, BN=256, BK=64; 256 thr (4 waves); grid 512 (2 blocks/CU, 72KB LDS).
// Double-buffered: X(k+1)->regs + glds W(k+1)->Bt[nxt] issued at step top,
// compute(cur), ds_write A(k+1)->Ab[nxt], barrier. Only loads get drained.
// Epilogue: bias + col-swizzled C in LDS -> frag-major Kfrag/Vfrag stores.
// ---------------------------------------------------------------------------
__global__ void __launch_bounds__(256, 2) proj_kernel(
    const float* __restrict__ X, const u16* __restrict__ Wtiles,
    const float* __restrict__ bk, const float* __restrict__ bv,
    u16* __restrict__ Kfrag, u16* __restrict__ Vfrag)
{
  __shared__ u16 Ab[2][32 * 64];    // 2 x 4 KB, XOR-swizzled rows
  __shared__ u16 Bt[2][256 * 64];   // 2 x 32 KB, pre-swizzled via Wtiles

  const int tid  = threadIdx.x;
  const int lane = tid & 63;
  const int wid  = tid >> 6;        // 0..3 = wn
  const int l15  = lane & 15;
  const int g    = lane >> 4;
  const int m0   = blockIdx.x * 32;

  const int ar = tid >> 3;          // 0..31  A-stage row
  const int ac = (tid & 7) * 8;     // col base (8 f32)

  const float* xrow  = X + (size_t)(m0 + ar) * DMS + ac;
  const int    abOff = (ar * 128 + ac * 2) ^ ((ar & 7) << 4);

  char* AbB = (char*)&Ab[0][0];
  char* BtB = (char*)&Bt[0][0];

  f32x4 acc[2][4];
#pragma unroll
  for (int i = 0; i < 2; ++i)
#pragma unroll
    for (int j = 0; j < 4; ++j) acc[i][j] = (f32x4){0.f, 0.f, 0.f, 0.f};

  float4 xv[2][2];

  // ---- prologue: X(0) -> regs -> Ab[0]; W(0) -> Bt[0] ----
  xv[0][0] = *(const float4*)(xrow);
  xv[0][1] = *(const float4*)(xrow + 4);
  {
    const u16* ws = Wtiles + wid * 4096 + lane * 8;
    u16* wd = &Bt[0][0] + wid * 4096;
#pragma unroll
    for (int r = 0; r < 8; ++r) glds16(ws + r * 512, wd + r * 512);
  }
  *(uint4*)(AbB + abOff) = pack8bf(xv[0][0], xv[0][1]);
  __syncthreads();

#pragma unroll
  for (int k = 0; k < 16; ++k) {
    const int cur = k & 1, nxt = cur ^ 1;
    // issue-ahead prefetch of step k+1 (regs + glds) — loads only
    if (k < 15) {
      xv[nxt][0] = *(const float4*)(xrow + (k + 1) * 64);
      xv[nxt][1] = *(const float4*)(xrow + (k + 1) * 64 + 4);
      const u16* ws = Wtiles + (size_t)(k + 1) * 16384 + wid * 4096 + lane * 8;
      u16* wd = &Bt[nxt][0] + wid * 4096;
#pragma unroll
      for (int r = 0; r < 8; ++r) glds16(ws + r * 512, wd + r * 512);
    }
    // compute step k from buffer cur
#pragma unroll
    for (int kh = 0; kh < 2; ++kh) {
      bf16x8 af[2], bfr[4];
#pragma unroll
      for (int mf = 0; mf < 2; ++mf) {
        int m = mf * 16 + l15;
        int ab = cur * 4096 + ((m * 128 + (kh * 32 + g * 8) * 2) ^ ((m & 7) << 4));
        U128 u; u.u4 = *(uint4*)(AbB + ab); af[mf] = u.b8;
      }
#pragma unroll
      for (int nf = 0; nf < 4; ++nf) {
        int n = wid * 64 + nf * 16 + l15;
        int bb = cur * 32768 + ((n * 128 + (kh * 32 + g * 8) * 2) ^ ((n & 7) << 4));
        U128 u; u.u4 = *(uint4*)(BtB + bb); bfr[nf] = u.b8;
      }
#pragma unroll
      for (int mf = 0; mf < 2; ++mf)
#pragma unroll
        for (int nf = 0; nf < 4; ++nf)
          acc[mf][nf] = mfma16(af[mf], bfr[nf], acc[mf][nf]);
    }
    // stage X(k+1) into Ab[nxt]
    if (k < 15)
      *(uint4*)(AbB + nxt * 4096 + abOff) = pack8bf(xv[nxt][0], xv[nxt][1]);
    __syncthreads();
  }

  // ---- epilogue: C -> Bt[0] (col-swizzled [32][256]) -> frag-major stores ----
  u16* Ct = &Bt[0][0];
#pragma unroll
  for (int nf = 0; nf < 4; ++nf) {
    int n = wid * 64 + nf * 16 + l15;
    float bias = (n < 128) ? bk[n] : bv[n - 128];
#pragma unroll
    for (int mf = 0; mf < 2; ++mf)
#pragma unroll
      for (int j = 0; j < 4; ++j) {
        int s = mf * 16 + g * 4 + j;
        Ct[s * 256 + (n ^ ((s & 7) << 3))] = f2bf(acc[mf][nf][j] + bias);
      }
  }
  __syncthreads();

  const int bb   = m0 >> 11;            // batch
  const int tloc = (m0 & 2047) >> 5;    // 32-row tile within batch

  // ---- Kfrag store: frag-major, contiguous runs ----
  {
    int sl = tid >> 3;   // 0..31
    int ks = tid & 7;    // 0..7
    u16* dst = Kfrag + (size_t)bb * BSTRIDE + (size_t)(tloc * 8 + ks) * 512 + sl * 8;
#pragma unroll
    for (int hi2 = 0; hi2 < 2; ++hi2) {
      int n = ks * 16 + hi2 * 8;
      uint4 v = *(const uint4*)&Ct[sl * 256 + (n ^ ((sl & 7) << 3))];
      *(uint4*)(dst + hi2 * 256) = v;
    }
  }
  // ---- Vfrag store: transpose out of C ----
  {
    int l31 = tid & 31;
    int vb2 = (tid >> 5) & 3;
    int th  = tid >> 7;   // 0..1
    int n   = 128 + vb2 * 32 + l31;
    u16* dst = Vfrag + (size_t)bb * BSTRIDE +
               (size_t)((tloc * 4 + vb2) * 2 + th) * 512 + l31 * 8;
#pragma unroll
    for (int hi = 0; hi < 2; ++hi) {
      U128 w;
#pragma unroll
      for (int j = 0; j < 8; ++j) {
        int s = th * 16 + hi * 8 + j;
        w.us[j] = Ct[s * 256 + (n ^ ((s & 7) << 3))];
      }
      *(uint4*)(dst + hi * 256) = w.u4;
    }
  }
}

// ---------------------------------------------------------------------------
// Kernel 2: causal flash attention + fused out[:, :1024] passthrough copy.
// Copy (32 float4/thread) interleaved 2/iter into the KV loop — stores are
// never drained (no in-loop barriers); remainder after the loop. Big-qt
// blocks dispatch first, absorbing copy fully in-loop; small-qt blocks drain
// while big blocks still compute.
// ---------------------------------------------------------------------------
__global__ void __launch_bounds__(256, 2) attn_kernel(
    const u16* __restrict__ Kfrag, const u16* __restrict__ Vfrag,
    const float* __restrict__ X, float* __restrict__ out)
{
  __shared__ float Om[4][128][33];   // [slice][v][q] partial O^T
  __shared__ float Ml[4][2][32];     // [slice][m|l][q]
  __shared__ float Wm[4][32];        // merge weights
  __shared__ float Li[32];           // 1/L

  const int tid  = threadIdx.x;
  const int lane = tid & 63;
  const int w    = tid >> 6;         // KV slice 0..3
  const int l31  = lane & 31;
  const int hi   = lane >> 5;

  const int bi = blockIdx.x;
  const int b  = bi & 7;
  const int qt = (bi < 256) ? (63 - (bi >> 3)) : ((bi >> 3) - 32);
  const int q0 = qt * 32;

  const u16* Kb = Kfrag + (size_t)b * BSTRIDE;
  const u16* Vb = Vfrag + (size_t)b * BSTRIDE;
  const int loff = hi * 256 + l31 * 8;   // lane offset within a 512-u16 frag

  // ---- passthrough copy setup: thread owns row q0+(tid>>3), 32 float4 ----
  const int cr = tid >> 3;
  const int cs = (tid & 7) * 32;     // float4 index within row
  const float4* csrc = (const float4*)(X + (size_t)(b * SEQ + q0 + cr) * DMS) + cs;
  float4*       cdst = (float4*)(out + (size_t)(b * SEQ + q0 + cr) * OD) + cs;
  int cidx = 0;

  bf16x8 qf[8];
  {
    const u16* qp = Kb + (size_t)(qt * 8) * 512 + loff;
#pragma unroll
    for (int ks = 0; ks < 8; ++ks) {
      U128 u; u.u4 = *(const uint4*)(qp + ks * 512); qf[ks] = u.b8;
    }
  }

  f32x16 o[4];
#pragma unroll
  for (int vb2 = 0; vb2 < 4; ++vb2)
#pragma unroll
    for (int i = 0; i < 16; ++i) o[vb2][i] = 0.f;

  float mrun = -3.0e38f, lsum = 0.f;
  const float SC  = 0.08838834764831845f;   // 1/sqrt(128)
  const float L2E = 1.44269504088896341f;

  bf16x8 kf[8];
  {
    int ti0 = (w <= qt) ? w : 0;
    const u16* kp = Kb + (size_t)(ti0 * 8) * 512 + loff;
#pragma unroll
    for (int ks = 0; ks < 8; ++ks) {
      U128 u; u.u4 = *(const uint4*)(kp + ks * 512); kf[ks] = u.b8;
    }
  }

  for (int ti = w; ti <= qt; ti += 4) {
    bf16x8 vf[4][2];
    {
      const u16* vp = Vb + (size_t)(ti * 8) * 512 + loff;
#pragma unroll
      for (int vb2 = 0; vb2 < 4; ++vb2)
#pragma unroll
        for (int th = 0; th < 2; ++th) {
          U128 u; u.u4 = *(const uint4*)(vp + (vb2 * 2 + th) * 512);
          vf[vb2][th] = u.b8;
        }
    }
    // ---- interleaved passthrough: 2 float4 per iteration ----
    if (cidx < 32) {
      float4 t0 = csrc[cidx], t1 = csrc[cidx + 1];
      cdst[cidx] = t0; cdst[cidx + 1] = t1;
      cidx += 2;
    }
    f32x16 s;
#pragma unroll
    for (int i = 0; i < 16; ++i) s[i] = 0.f;
#pragma unroll
    for (int ks = 0; ks < 8; ++ks) s = mfma32(kf[ks], qf[ks], s);
    {
      int tin = (ti + 4 <= qt) ? ti + 4 : ti;
      const u16* kp = Kb + (size_t)(tin * 8) * 512 + loff;
#pragma unroll
      for (int ks = 0; ks < 8; ++ks) {
        U128 u; u.u4 = *(const uint4*)(kp + ks * 512); kf[ks] = u.b8;
      }
    }
    float sv[16];
#pragma unroll
    for (int r = 0; r < 16; ++r) sv[r] = s[r] * SC;
    if (ti == qt) {
#pragma unroll
      for (int r = 0; r < 16; ++r) {
        int toff = (r & 3) + 8 * (r >> 2) + 4 * hi;
        if (toff > l31) sv[r] = -3.0e38f;
      }
    }
    float mx = sv[0];
#pragma unroll
    for (int r = 1; r < 16; ++r) mx = fmaxf(mx, sv[r]);
    mx = fmaxf(mx, __shfl_xor(mx, 32));
    float p[16];
    float ps = 0.f;
    if (__all(mx - mrun <= 8.0f)) {
#pragma unroll
      for (int r = 0; r < 16; ++r) { p[r] = fexp2((sv[r] - mrun) * L2E); ps += p[r]; }
      ps += __shfl_xor(ps, 32);
      lsum += ps;
    } else {
      float mnew = fmaxf(mrun, mx);
      float al = fexp2((mrun - mnew) * L2E);
#pragma unroll
      for (int r = 0; r < 16; ++r) { p[r] = fexp2((sv[r] - mnew) * L2E); ps += p[r]; }
      ps += __shfl_xor(ps, 32);
      lsum = lsum * al + ps;
      mrun = mnew;
#pragma unroll
      for (int vb2 = 0; vb2 < 4; ++vb2)
#pragma unroll
        for (int i = 0; i < 16; ++i) o[vb2][i] *= al;
    }
    u32 c01 = (u32)f2bf(p[0])  | ((u32)f2bf(p[1])  << 16);
    u32 c23 = (u32)f2bf(p[2])  | ((u32)f2bf(p[3])  << 16);
    u32 c45 = (u32)f2bf(p[4])  | ((u32)f2bf(p[5])  << 16);
    u32 c67 = (u32)f2bf(p[6])  | ((u32)f2bf(p[7])  << 16);
    u32 c89 = (u32)f2bf(p[8])  | ((u32)f2bf(p[9])  << 16);
    u32 cAB = (u32)f2bf(p[10]) | ((u32)f2bf(p[11]) << 16);
    u32 cCD = (u32)f2bf(p[12]) | ((u32)f2bf(p[13]) << 16);
    u32 cEF = (u32)f2bf(p[14]) | ((u32)f2bf(p[15]) << 16);
    u32 d01 = __shfl_xor(c01, 32);
    u32 d23 = __shfl_xor(c23, 32);
    u32 d45 = __shfl_xor(c45, 32);
    u32 d67 = __shfl_xor(c67, 32);
    u32 d89 = __shfl_xor(c89, 32);
    u32 dAB = __shfl_xor(cAB, 32);
    u32 dCD = __shfl_xor(cCD, 32);
    u32 dEF = __shfl_xor(cEF, 32);
    U128 pf1, pf2;
    pf1.u[0] = hi ? d45 : c01;
    pf1.u[1] = hi ? d67 : c23;
    pf1.u[2] = hi ? c45 : d01;
    pf1.u[3] = hi ? c67 : d23;
    pf2.u[0] = hi ? dCD : c89;
    pf2.u[1] = hi ? dEF : cAB;
    pf2.u[2] = hi ? cCD : d89;
    pf2.u[3] = hi ? cEF : dAB;
#pragma unroll
    for (int vb2 = 0; vb2 < 4; ++vb2) {
      o[vb2] = mfma32(vf[vb2][0], pf1.b8, o[vb2]);
      o[vb2] = mfma32(vf[vb2][1], pf2.b8, o[vb2]);
    }
  }

  // ---- drain remaining passthrough copy (4 float4 per round) ----
  for (; cidx < 32; cidx += 4) {
    float4 t0 = csrc[cidx], t1 = csrc[cidx + 1];
    float4 t2 = csrc[cidx + 2], t3 = csrc[cidx + 3];
    cdst[cidx] = t0; cdst[cidx + 1] = t1;
    cdst[cidx + 2] = t2; cdst[cidx + 3] = t3;
  }

  // ---- publish partials ----
#pragma unroll
  for (int vb2 = 0; vb2 < 4; ++vb2)
#pragma unroll
    for (int r = 0; r < 16; ++r) {
      int v = vb2 * 32 + (r & 3) + 8 * (r >> 2) + 4 * hi;
      Om[w][v][l31] = o[vb2][r];
    }
  if (lane < 32) {
    Ml[w][0][l31] = mrun;
    Ml[w][1][l31] = lsum;
  }
  __syncthreads();

  if (tid < 32) {
    float m0 = Ml[0][0][tid], m1 = Ml[1][0][tid];
    float m2 = Ml[2][0][tid], m3 = Ml[3][0][tid];
    float M  = fmaxf(fmaxf(m0, m1), fmaxf(m2, m3));
    float w0 = fexp2((m0 - M) * L2E), w1 = fexp2((m1 - M) * L2E);
    float w2 = fexp2((m2 - M) * L2E), w3 = fexp2((m3 - M) * L2E);
    float L  = Ml[0][1][tid] * w0 + Ml[1][1][tid] * w1 +
               Ml[2][1][tid] * w2 + Ml[3][1][tid] * w3;
    Wm[0][tid] = w0; Wm[1][tid] = w1; Wm[2][tid] = w2; Wm[3][tid] = w3;
    Li[tid] = 1.f / L;
  }
  __syncthreads();

  {
    const int q = tid >> 3;
    const int vbase = (tid & 7) * 16;
    float wq0 = Wm[0][q], wq1 = Wm[1][q], wq2 = Wm[2][q], wq3 = Wm[3][q];
    float li = Li[q];
    float* orow = out + (size_t)(b * SEQ + q0 + q) * OD + 1024 + vbase;
#pragma unroll
    for (int i = 0; i < 16; i += 4) {
      float4 res;
      res.x = (Om[0][vbase + i + 0][q] * wq0 + Om[1][vbase + i + 0][q] * wq1 +
               Om[2][vbase + i + 0][q] * wq2 + Om[3][vbase + i + 0][q] * wq3) * li;
      res.y = (Om[0][vbase + i + 1][q] * wq0 + Om[1][vbase + i + 1][q] * wq1 +
               Om[2][vbase + i + 1][q] * wq2 + Om[3][vbase + i + 1][q] * wq3) * li;
      res.z = (Om[0][vbase + i + 2][q] * wq0 + Om[1][vbase + i + 2][q] * wq1 +
               Om[2][vbase + i + 2][q] * wq2 + Om[3][vbase + i + 2][q] * wq3) * li;
      res.w = (Om[0][vbase + i + 3][q] * wq0 + Om[1][vbase + i + 3][q] * wq1 +
               Om[2][vbase + i + 3][q] * wq2 + Om[3][vbase + i + 3][q] * wq3) * li;
      *(float4*)(orow + i) = res;
    }
  }
}

extern "C" void kernel_launch(void* const* d_in, const int* in_sizes, int n_in,
                              void* d_out, int out_size, void* d_ws, size_t ws_size,
                              hipStream_t stream)
{
  const float* X  = (const float*)d_in[0];
  const float* Wk = (const float*)d_in[1];
  const float* bk = (const float*)d_in[2];
  const float* Wv = (const float*)d_in[3];
  const float* bv = (const float*)d_in[4];
  float* out = (float*)d_out;

  u16* Kfrag  = (u16*)d_ws;                                // 4 MB
  u16* Vfrag  = Kfrag + (size_t)BATCH * BSTRIDE;           // 4 MB
  u16* Wtiles = Vfrag + (size_t)BATCH * BSTRIDE;           // 512 KB

  prep_kernel<<<dim3(128), dim3(256), 0, stream>>>(Wk, Wv, Wtiles);
  proj_kernel<<<dim3(512), dim3(256), 0, stream>>>(X, Wtiles, bk, bv, Kfrag, Vfrag);
  attn_kernel<<<dim3(512), dim3(256), 0, stream>>>(Kfrag, Vfrag, X, out);
}

// Round 9
// 69.224 us; speedup vs baseline: 1.4467x; 1.4467x over previous
//
#include <hip/hip_runtime.h>
#include <hip/hip_bf16.h>

#define BATCH 8
#define SEQ   2048
#define DMS   1024
#define KSZ   128
#define OD    1152   // 1024 + 128

typedef unsigned short u16;
typedef unsigned int   u32;
typedef __attribute__((ext_vector_type(4)))  float  f32x4;
typedef __attribute__((ext_vector_type(16))) float  f32x16;
typedef __attribute__((ext_vector_type(8)))  __bf16 bf16x8;

union U128 { uint4 u4; bf16x8 b8; u16 us[8]; u32 u[4]; };

__device__ inline u16 f2bf(float f) {
  union { __bf16 h; u16 u; } c;
  c.h = (__bf16)f;
  return c.u;
}

__device__ inline float fexp2(float x) {
  float r;
  asm("v_exp_f32 %0, %1" : "=v"(r) : "v"(x));
  return r;
}

__device__ inline f32x4 mfma16(bf16x8 a, bf16x8 b, f32x4 c) {
  return __builtin_amdgcn_mfma_f32_16x16x32_bf16(a, b, c, 0, 0, 0);
}
__device__ inline f32x16 mfma32(bf16x8 a, bf16x8 b, f32x16 c) {
  return __builtin_amdgcn_mfma_f32_32x32x16_bf16(a, b, c, 0, 0, 0);
}

__device__ inline uint4 pack8bf(float4 a, float4 b) {
  U128 w;
  w.us[0] = f2bf(a.x); w.us[1] = f2bf(a.y);
  w.us[2] = f2bf(a.z); w.us[3] = f2bf(a.w);
  w.us[4] = f2bf(b.x); w.us[5] = f2bf(b.y);
  w.us[6] = f2bf(b.z); w.us[7] = f2bf(b.w);
  return w.u4;
}

__device__ inline void glds16(const u16* src, u16* ldsDst) {
  __builtin_amdgcn_global_load_lds(
      (const __attribute__((address_space(1))) u32*)src,
      (__attribute__((address_space(3))) u32*)ldsDst, 16, 0, 0);
}

// Fragment-major layouts (per batch, stride 262144 u16 = 512 KB):
//   Kfrag[(t2*8+ks)*512 + hi*256 + l31*8 + j]          = K[t2*32+l31][ks*16+hi*8+j]
//   Vfrag[((t2*4+vb2)*2+th)*512 + hi*256 + l31*8 + j]  = V[t2*32+th*16+hi*8+j][vb2*32+l31]
#define BSTRIDE 262144

// ---------------------------------------------------------------------------
// Kernel 0: prep — [Wk|Wv] f32 -> bf16 tiles in proj's exact LDS byte order.
// ---------------------------------------------------------------------------
__global__ void __launch_bounds__(256) prep_kernel(
    const float* __restrict__ Wk, const float* __restrict__ Wv,
    u16* __restrict__ Wtiles)
{
  int T = blockIdx.x * 256 + threadIdx.x;   // 0..32767
  int n  = T & 255;
  int kc = (T >> 8) * 8;                    // 0..1016 step 8
  int ks = kc >> 6;
  int kk = kc & 63;
  const float* src = (n < 128) ? (Wk + n) : (Wv + (n - 128));
  U128 w;
#pragma unroll
  for (int j = 0; j < 8; ++j) w.us[j] = f2bf(src[(size_t)(kc + j) * KSZ]);
  u16* dst = Wtiles + ks * 16384 + n * 64 + (kk ^ ((n & 7) << 3));
  *(uint4*)dst = w.u4;
}

// ---------------------------------------------------------------------------
// Kernel 1: fused K/V projection — NO STORES IN THE BARRIERED LOOP (verified
// R8: 52us -> ~8us once stores left the loop). BM=32, BN=256, BK=64; 256 thr;
// grid 512 (2 blocks/CU). Double-buffered loads only; frag stores in epilogue.
// ---------------------------------------------------------------------------
__global__ void __launch_bounds__(256, 2) proj_kernel(
    const float* __restrict__ X, const u16* __restrict__ Wtiles,
    const float* __restrict__ bk, const float* __restrict__ bv,
    u16* __restrict__ Kfrag, u16* __restrict__ Vfrag)
{
  __shared__ u16 Ab[2][32 * 64];    // 2 x 4 KB, XOR-swizzled rows
  __shared__ u16 Bt[2][256 * 64];   // 2 x 32 KB, pre-swizzled via Wtiles

  const int tid  = threadIdx.x;
  const int lane = tid & 63;
  const int wid  = tid >> 6;        // 0..3 = wn
  const int l15  = lane & 15;
  const int g    = lane >> 4;
  const int m0   = blockIdx.x * 32;

  const int ar = tid >> 3;          // 0..31  A-stage row
  const int ac = (tid & 7) * 8;     // col base (8 f32)

  const float* xrow  = X + (size_t)(m0 + ar) * DMS + ac;
  const int    abOff = (ar * 128 + ac * 2) ^ ((ar & 7) << 4);

  char* AbB = (char*)&Ab[0][0];
  char* BtB = (char*)&Bt[0][0];

  f32x4 acc[2][4];
#pragma unroll
  for (int i = 0; i < 2; ++i)
#pragma unroll
    for (int j = 0; j < 4; ++j) acc[i][j] = (f32x4){0.f, 0.f, 0.f, 0.f};

  float4 xv[2][2];

  // ---- prologue: X(0) -> regs -> Ab[0]; W(0) -> Bt[0] ----
  xv[0][0] = *(const float4*)(xrow);
  xv[0][1] = *(const float4*)(xrow + 4);
  {
    const u16* ws = Wtiles + wid * 4096 + lane * 8;
    u16* wd = &Bt[0][0] + wid * 4096;
#pragma unroll
    for (int r = 0; r < 8; ++r) glds16(ws + r * 512, wd + r * 512);
  }
  *(uint4*)(AbB + abOff) = pack8bf(xv[0][0], xv[0][1]);
  __syncthreads();

#pragma unroll
  for (int k = 0; k < 16; ++k) {
    const int cur = k & 1, nxt = cur ^ 1;
    // issue-ahead prefetch of step k+1 (loads only)
    if (k < 15) {
      xv[nxt][0] = *(const float4*)(xrow + (k + 1) * 64);
      xv[nxt][1] = *(const float4*)(xrow + (k + 1) * 64 + 4);
      const u16* ws = Wtiles + (size_t)(k + 1) * 16384 + wid * 4096 + lane * 8;
      u16* wd = &Bt[nxt][0] + wid * 4096;
#pragma unroll
      for (int r = 0; r < 8; ++r) glds16(ws + r * 512, wd + r * 512);
    }
    // compute step k from buffer cur
#pragma unroll
    for (int kh = 0; kh < 2; ++kh) {
      bf16x8 af[2], bfr[4];
#pragma unroll
      for (int mf = 0; mf < 2; ++mf) {
        int m = mf * 16 + l15;
        int ab = cur * 4096 + ((m * 128 + (kh * 32 + g * 8) * 2) ^ ((m & 7) << 4));
        U128 u; u.u4 = *(uint4*)(AbB + ab); af[mf] = u.b8;
      }
#pragma unroll
      for (int nf = 0; nf < 4; ++nf) {
        int n = wid * 64 + nf * 16 + l15;
        int bb = cur * 32768 + ((n * 128 + (kh * 32 + g * 8) * 2) ^ ((n & 7) << 4));
        U128 u; u.u4 = *(uint4*)(BtB + bb); bfr[nf] = u.b8;
      }
#pragma unroll
      for (int mf = 0; mf < 2; ++mf)
#pragma unroll
        for (int nf = 0; nf < 4; ++nf)
          acc[mf][nf] = mfma16(af[mf], bfr[nf], acc[mf][nf]);
    }
    // stage X(k+1) into Ab[nxt]
    if (k < 15)
      *(uint4*)(AbB + nxt * 4096 + abOff) = pack8bf(xv[nxt][0], xv[nxt][1]);
    __syncthreads();
  }

  // ---- epilogue: C -> Bt[0] (col-swizzled [32][256]) -> frag-major stores ----
  u16* Ct = &Bt[0][0];
#pragma unroll
  for (int nf = 0; nf < 4; ++nf) {
    int n = wid * 64 + nf * 16 + l15;
    float bias = (n < 128) ? bk[n] : bv[n - 128];
#pragma unroll
    for (int mf = 0; mf < 2; ++mf)
#pragma unroll
      for (int j = 0; j < 4; ++j) {
        int s = mf * 16 + g * 4 + j;
        Ct[s * 256 + (n ^ ((s & 7) << 3))] = f2bf(acc[mf][nf][j] + bias);
      }
  }
  __syncthreads();

  const int bb   = m0 >> 11;            // batch
  const int tloc = (m0 & 2047) >> 5;    // 32-row tile within batch

  // ---- Kfrag store: frag-major, contiguous runs ----
  {
    int sl = tid >> 3;   // 0..31
    int ks = tid & 7;    // 0..7
    u16* dst = Kfrag + (size_t)bb * BSTRIDE + (size_t)(tloc * 8 + ks) * 512 + sl * 8;
#pragma unroll
    for (int hi2 = 0; hi2 < 2; ++hi2) {
      int n = ks * 16 + hi2 * 8;
      uint4 v = *(const uint4*)&Ct[sl * 256 + (n ^ ((sl & 7) << 3))];
      *(uint4*)(dst + hi2 * 256) = v;
    }
  }
  // ---- Vfrag store: transpose out of C ----
  {
    int l31 = tid & 31;
    int vb2 = (tid >> 5) & 3;
    int th  = tid >> 7;   // 0..1
    int n   = 128 + vb2 * 32 + l31;
    u16* dst = Vfrag + (size_t)bb * BSTRIDE +
               (size_t)((tloc * 4 + vb2) * 2 + th) * 512 + l31 * 8;
#pragma unroll
    for (int hi = 0; hi < 2; ++hi) {
      U128 w;
#pragma unroll
      for (int j = 0; j < 8; ++j) {
        int s = th * 16 + hi * 8 + j;
        w.us[j] = Ct[s * 256 + (n ^ ((s & 7) << 3))];
      }
      *(uint4*)(dst + hi * 256) = w.u4;
    }
  }
}

// ---------------------------------------------------------------------------
// Kernel 2: causal flash attention + TAIL passthrough copy.
// The copy (this block's 32 rows of out[:, :1024] = X) runs at the very end,
// after all barriers/output writes — its stores are never waited on by any
// in-loop vmcnt (R8 lesson: vmcnt is in-order; in-loop interleave serializes).
// Row-at-a-time addressing: each instruction covers contiguous 1KB per wave.
// Overlap: light-qt blocks finish compute early and stream their copy while
// paired heavy-qt blocks still compute.
// ---------------------------------------------------------------------------
__global__ void __launch_bounds__(256, 2) attn_kernel(
    const u16* __restrict__ Kfrag, const u16* __restrict__ Vfrag,
    const float* __restrict__ X, float* __restrict__ out)
{
  __shared__ float Om[4][128][33];   // [slice][v][q] partial O^T
  __shared__ float Ml[4][2][32];     // [slice][m|l][q]
  __shared__ float Wm[4][32];        // merge weights
  __shared__ float Li[32];           // 1/L

  const int tid  = threadIdx.x;
  const int lane = tid & 63;
  const int w    = tid >> 6;         // KV slice 0..3
  const int l31  = lane & 31;
  const int hi   = lane >> 5;

  const int bi = blockIdx.x;
  const int b  = bi & 7;
  const int qt = (bi < 256) ? (63 - (bi >> 3)) : ((bi >> 3) - 32);
  const int q0 = qt * 32;

  const u16* Kb = Kfrag + (size_t)b * BSTRIDE;
  const u16* Vb = Vfrag + (size_t)b * BSTRIDE;
  const int loff = hi * 256 + l31 * 8;   // lane offset within a 512-u16 frag

  bf16x8 qf[8];
  {
    const u16* qp = Kb + (size_t)(qt * 8) * 512 + loff;
#pragma unroll
    for (int ks = 0; ks < 8; ++ks) {
      U128 u; u.u4 = *(const uint4*)(qp + ks * 512); qf[ks] = u.b8;
    }
  }

  f32x16 o[4];
#pragma unroll
  for (int vb2 = 0; vb2 < 4; ++vb2)
#pragma unroll
    for (int i = 0; i < 16; ++i) o[vb2][i] = 0.f;

  float mrun = -3.0e38f, lsum = 0.f;
  const float SC  = 0.08838834764831845f;   // 1/sqrt(128)
  const float L2E = 1.44269504088896341f;

  bf16x8 kf[8];
  {
    int ti0 = (w <= qt) ? w : 0;
    const u16* kp = Kb + (size_t)(ti0 * 8) * 512 + loff;
#pragma unroll
    for (int ks = 0; ks < 8; ++ks) {
      U128 u; u.u4 = *(const uint4*)(kp + ks * 512); kf[ks] = u.b8;
    }
  }

  for (int ti = w; ti <= qt; ti += 4) {
    bf16x8 vf[4][2];
    {
      const u16* vp = Vb + (size_t)(ti * 8) * 512 + loff;
#pragma unroll
      for (int vb2 = 0; vb2 < 4; ++vb2)
#pragma unroll
        for (int th = 0; th < 2; ++th) {
          U128 u; u.u4 = *(const uint4*)(vp + (vb2 * 2 + th) * 512);
          vf[vb2][th] = u.b8;
        }
    }
    f32x16 s;
#pragma unroll
    for (int i = 0; i < 16; ++i) s[i] = 0.f;
#pragma unroll
    for (int ks = 0; ks < 8; ++ks) s = mfma32(kf[ks], qf[ks], s);
    {
      int tin = (ti + 4 <= qt) ? ti + 4 : ti;
      const u16* kp = Kb + (size_t)(tin * 8) * 512 + loff;
#pragma unroll
      for (int ks = 0; ks < 8; ++ks) {
        U128 u; u.u4 = *(const uint4*)(kp + ks * 512); kf[ks] = u.b8;
      }
    }
    float sv[16];
#pragma unroll
    for (int r = 0; r < 16; ++r) sv[r] = s[r] * SC;
    if (ti == qt) {
#pragma unroll
      for (int r = 0; r < 16; ++r) {
        int toff = (r & 3) + 8 * (r >> 2) + 4 * hi;
        if (toff > l31) sv[r] = -3.0e38f;
      }
    }
    float mx = sv[0];
#pragma unroll
    for (int r = 1; r < 16; ++r) mx = fmaxf(mx, sv[r]);
    mx = fmaxf(mx, __shfl_xor(mx, 32));
    float p[16];
    float ps = 0.f;
    if (__all(mx - mrun <= 8.0f)) {
#pragma unroll
      for (int r = 0; r < 16; ++r) { p[r] = fexp2((sv[r] - mrun) * L2E); ps += p[r]; }
      ps += __shfl_xor(ps, 32);
      lsum += ps;
    } else {
      float mnew = fmaxf(mrun, mx);
      float al = fexp2((mrun - mnew) * L2E);
#pragma unroll
      for (int r = 0; r < 16; ++r) { p[r] = fexp2((sv[r] - mnew) * L2E); ps += p[r]; }
      ps += __shfl_xor(ps, 32);
      lsum = lsum * al + ps;
      mrun = mnew;
#pragma unroll
      for (int vb2 = 0; vb2 < 4; ++vb2)
#pragma unroll
        for (int i = 0; i < 16; ++i) o[vb2][i] *= al;
    }
    u32 c01 = (u32)f2bf(p[0])  | ((u32)f2bf(p[1])  << 16);
    u32 c23 = (u32)f2bf(p[2])  | ((u32)f2bf(p[3])  << 16);
    u32 c45 = (u32)f2bf(p[4])  | ((u32)f2bf(p[5])  << 16);
    u32 c67 = (u32)f2bf(p[6])  | ((u32)f2bf(p[7])  << 16);
    u32 c89 = (u32)f2bf(p[8])  | ((u32)f2bf(p[9])  << 16);
    u32 cAB = (u32)f2bf(p[10]) | ((u32)f2bf(p[11]) << 16);
    u32 cCD = (u32)f2bf(p[12]) | ((u32)f2bf(p[13]) << 16);
    u32 cEF = (u32)f2bf(p[14]) | ((u32)f2bf(p[15]) << 16);
    u32 d01 = __shfl_xor(c01, 32);
    u32 d23 = __shfl_xor(c23, 32);
    u32 d45 = __shfl_xor(c45, 32);
    u32 d67 = __shfl_xor(c67, 32);
    u32 d89 = __shfl_xor(c89, 32);
    u32 dAB = __shfl_xor(cAB, 32);
    u32 dCD = __shfl_xor(cCD, 32);
    u32 dEF = __shfl_xor(cEF, 32);
    U128 pf1, pf2;
    pf1.u[0] = hi ? d45 : c01;
    pf1.u[1] = hi ? d67 : c23;
    pf1.u[2] = hi ? c45 : d01;
    pf1.u[3] = hi ? c67 : d23;
    pf2.u[0] = hi ? dCD : c89;
    pf2.u[1] = hi ? dEF : cAB;
    pf2.u[2] = hi ? cCD : d89;
    pf2.u[3] = hi ? cEF : dAB;
#pragma unroll
    for (int vb2 = 0; vb2 < 4; ++vb2) {
      o[vb2] = mfma32(vf[vb2][0], pf1.b8, o[vb2]);
      o[vb2] = mfma32(vf[vb2][1], pf2.b8, o[vb2]);
    }
  }

  // ---- publish partials ----
#pragma unroll
  for (int vb2 = 0; vb2 < 4; ++vb2)
#pragma unroll
    for (int r = 0; r < 16; ++r) {
      int v = vb2 * 32 + (r & 3) + 8 * (r >> 2) + 4 * hi;
      Om[w][v][l31] = o[vb2][r];
    }
  if (lane < 32) {
    Ml[w][0][l31] = mrun;
    Ml[w][1][l31] = lsum;
  }
  __syncthreads();

  if (tid < 32) {
    float m0 = Ml[0][0][tid], m1 = Ml[1][0][tid];
    float m2 = Ml[2][0][tid], m3 = Ml[3][0][tid];
    float M  = fmaxf(fmaxf(m0, m1), fmaxf(m2, m3));
    float w0 = fexp2((m0 - M) * L2E), w1 = fexp2((m1 - M) * L2E);
    float w2 = fexp2((m2 - M) * L2E), w3 = fexp2((m3 - M) * L2E);
    float L  = Ml[0][1][tid] * w0 + Ml[1][1][tid] * w1 +
               Ml[2][1][tid] * w2 + Ml[3][1][tid] * w3;
    Wm[0][tid] = w0; Wm[1][tid] = w1; Wm[2][tid] = w2; Wm[3][tid] = w3;
    Li[tid] = 1.f / L;
  }
  __syncthreads();

  {
    const int q = tid >> 3;
    const int vbase = (tid & 7) * 16;
    float wq0 = Wm[0][q], wq1 = Wm[1][q], wq2 = Wm[2][q], wq3 = Wm[3][q];
    float li = Li[q];
    float* orow = out + (size_t)(b * SEQ + q0 + q) * OD + 1024 + vbase;
#pragma unroll
    for (int i = 0; i < 16; i += 4) {
      float4 res;
      res.x = (Om[0][vbase + i + 0][q] * wq0 + Om[1][vbase + i + 0][q] * wq1 +
               Om[2][vbase + i + 0][q] * wq2 + Om[3][vbase + i + 0][q] * wq3) * li;
      res.y = (Om[0][vbase + i + 1][q] * wq0 + Om[1][vbase + i + 1][q] * wq1 +
               Om[2][vbase + i + 1][q] * wq2 + Om[3][vbase + i + 1][q] * wq3) * li;
      res.z = (Om[0][vbase + i + 2][q] * wq0 + Om[1][vbase + i + 2][q] * wq1 +
               Om[2][vbase + i + 2][q] * wq2 + Om[3][vbase + i + 2][q] * wq3) * li;
      res.w = (Om[0][vbase + i + 3][q] * wq0 + Om[1][vbase + i + 3][q] * wq1 +
               Om[2][vbase + i + 3][q] * wq2 + Om[3][vbase + i + 3][q] * wq3) * li;
      *(float4*)(orow + i) = res;
    }
  }

  // ---- TAIL passthrough copy: out[:, :1024] = X for this block's 32 rows.
  // Row r per pass: 256 threads x float4 = one full 4KB row, contiguous.
  {
#pragma unroll
    for (int r0 = 0; r0 < 32; r0 += 8) {
      float4 t[8];
#pragma unroll
      for (int j = 0; j < 8; ++j)
        t[j] = *((const float4*)(X + (size_t)(b * SEQ + q0 + r0 + j) * DMS) + tid);
#pragma unroll
      for (int j = 0; j < 8; ++j)
        *((float4*)(out + (size_t)(b * SEQ + q0 + r0 + j) * OD) + tid) = t[j];
    }
  }
}

extern "C" void kernel_launch(void* const* d_in, const int* in_sizes, int n_in,
                              void* d_out, int out_size, void* d_ws, size_t ws_size,
                              hipStream_t stream)
{
  const float* X  = (const float*)d_in[0];
  const float* Wk = (const float*)d_in[1];
  const float* bk = (const float*)d_in[2];
  const float* Wv = (const float*)d_in[3];
  const float* bv = (const float*)d_in[4];
  float* out = (float*)d_out;

  u16* Kfrag  = (u16*)d_ws;                                // 4 MB
  u16* Vfrag  = Kfrag + (size_t)BATCH * BSTRIDE;           // 4 MB
  u16* Wtiles = Vfrag + (size_t)BATCH * BSTRIDE;           // 512 KB

  prep_kernel<<<dim3(128), dim3(256), 0, stream>>>(Wk, Wv, Wtiles);
  proj_kernel<<<dim3(512), dim3(256), 0, stream>>>(X, Wtiles, bk, bv, Kfrag, Vfrag);
  attn_kernel<<<dim3(512), dim3(256), 0, stream>>>(Kfrag, Vfrag, X, out);
}